// Round 9
// baseline (347.856 us; speedup 1.0000x reference)
//
#include <hip/hip_runtime.h>

#define DIM 256
#define RPB 32            // dst rows per bucket
#define LOG_RPB 5
#define NG 8              // XCD groups: g=(e>>8)&7 == blockIdx&7 (grid%8==0)
#define BATCH 16
#define CAP 128           // slab capacity per (g,bucket) cell; Poisson(<=40) -> 14 sigma
#define BCAP 512          // sorted capacity per bucket; Poisson(<=320) -> 10.7 sigma
#define PC_B 3072         // place_conv blocks (%8==0 keeps g == blockIdx&7 == XCD)

typedef float f32x4 __attribute__((ext_vector_type(4)));
typedef unsigned int u32;
typedef unsigned short u16;

__device__ __forceinline__ u16 f32_to_bf16_rne(float f) {
    u32 u = __float_as_uint(f);
    return (u16)((u + 0x7FFFu + ((u >> 16) & 1u)) >> 16);
}

// ---------- fused slab placement + convert: BOTH roles in EVERY block ----------
// Phase 1 (place) is latency/atomic-bound, phase 2 (convert) is BW-bound; running
// them back-to-back in each block load-balances the whole GPU (no idle half).
// XCD-locality: stride = PC_B*256, (stride>>8)%8==0, so g=(e>>8)&7 == blockIdx&7
// == this block's XCD for every edge it touches -> cnt/binned lines stay in one L2.

__global__ void place_conv(const int* __restrict__ sA, const int* __restrict__ dA,
                           const int* __restrict__ sB, const int* __restrict__ dB,
                           int* __restrict__ cnt, u32* __restrict__ binned,
                           int TBc, int NBA_, int E1, int Etot,
                           const float* __restrict__ xin, u16* __restrict__ xbf,
                           long long n4) {
    // ---- phase 1: place (all blocks) ----
    {
        int stride = (int)gridDim.x * (int)blockDim.x;           // 786432; >>8 %8==0
        for (int e = (int)blockIdx.x * (int)blockDim.x + (int)threadIdx.x;
             e < Etot; e += stride) {
            int g = (e >> 8) & (NG - 1);                         // == blockIdx&7 == XCD
            int s, d, b;
            if (e < E1) {
                s = __builtin_nontemporal_load(sA + e);
                d = __builtin_nontemporal_load(dA + e);
                b = d >> LOG_RPB;
            } else {
                int e2 = e - E1;
                s = __builtin_nontemporal_load(sB + e2);
                d = __builtin_nontemporal_load(dB + e2);
                b = NBA_ + (d >> LOG_RPB);
            }
            int cell = g * TBc + b;
            int old = atomicAdd(&cnt[cell], 1);                  // XCD-private counter
            if (old < CAP)
                binned[(long long)cell * CAP + old] = ((u32)s << LOG_RPB) | (u32)(d & (RPB - 1));
        }
    }
    // ---- phase 2: convert x_paper f32 -> bf16 (all blocks; independent, no barrier) ----
    {
        long long stride = (long long)gridDim.x * blockDim.x;
        for (long long i = (long long)blockIdx.x * blockDim.x + threadIdx.x;
             i < n4; i += stride) {
            f32x4 v = __builtin_nontemporal_load((const f32x4*)xin + i);
            ushort4 o;
            o.x = f32_to_bf16_rne(v.x); o.y = f32_to_bf16_rne(v.y);
            o.z = f32_to_bf16_rne(v.z); o.w = f32_to_bf16_rne(v.w);
            *((ushort4*)xbf + i) = o;                            // re-read by gather1
        }
    }
}

// ---------- bucket sort body: 8 slabs -> bucket-padded `sorted` + 33-stride rp ----------

__device__ __forceinline__ void sort_bucket(int b, const u32* __restrict__ binned,
                                            const int* __restrict__ cnt,
                                            int* __restrict__ sorted,
                                            int* __restrict__ rp33, int TBc) {
    __shared__ int c[RPB];
    __shared__ int cur[RPB];
    int tid = threadIdx.x;
    if (tid < RPB) c[tid] = 0;
    __syncthreads();
#pragma unroll
    for (int g = 0; g < NG; ++g) {
        int cell = g * TBc + b;
        int n = cnt[cell]; n = (n < CAP) ? n : CAP;
        long long base = (long long)cell * CAP;
        for (int i = tid; i < n; i += 256)
            atomicAdd(&c[binned[base + i] & (RPB - 1)], 1);
    }
    __syncthreads();
    if (tid == 0) {
        int run = b * BCAP;
        for (int r = 0; r < RPB; ++r) {
            cur[r] = run;
            rp33[b * 33 + r] = run;
            run += c[r];
        }
        rp33[b * 33 + RPB] = run;
    }
    __syncthreads();
#pragma unroll
    for (int g = 0; g < NG; ++g) {
        int cell = g * TBc + b;
        int n = cnt[cell]; n = (n < CAP) ? n : CAP;
        long long base = (long long)cell * CAP;
        for (int i = tid; i < n; i += 256) {
            u32 e = binned[base + i];
            int pos = atomicAdd(&cur[e & (RPB - 1)], 1);   // native LDS int atomic
            sorted[pos] = (int)(e >> LOG_RPB);
        }
    }
}

__global__ void local_sortA(const u32* __restrict__ binned, const int* __restrict__ cnt,
                            int* __restrict__ sorted, int* __restrict__ rp33, int TBc) {
    sort_bucket(blockIdx.x, binned, cnt, sorted, rp33, TBc);
}

// ---------- gather body: issue ALL batch loads first (vv[16] = 32 VGPR in flight),
// then masked-fmaf accumulate. Lanes j>=cnt hold a duplicate of edge cnt-1 (clamped
// li), so their loads are same-address L1 hits and their contribution is masked. ----

template <bool DBF>
__device__ __forceinline__ void gather_body(const u16* __restrict__ xv,
                                            const int* __restrict__ rp33,
                                            const int* __restrict__ sorted_src,
                                            void* __restrict__ outv, int n, int blk) {
    int gtid = blk * 256 + (int)threadIdx.x;
    int r = gtid >> 6;
    int lane = gtid & 63;
    if (r >= n) return;
    int bi = (r >> LOG_RPB) * 33 + (r & (RPB - 1));
    int beg = rp33[bi];
    int end = rp33[bi + 1];
    float ax = 0.f, ay = 0.f, az = 0.f, aw = 0.f;
    for (int i = beg; i < end; i += BATCH) {
        int cnt = end - i;
        cnt = (cnt < BATCH) ? cnt : BATCH;
        int li = (lane < cnt) ? lane : (cnt - 1);
        int sid = sorted_src[i + li];
        uint2 vv[BATCH];
#pragma unroll
        for (int j = 0; j < BATCH; ++j) {                    // issue phase: 16 loads in flight
            int s = __builtin_amdgcn_readlane(sid, j);       // SGPR broadcast
            vv[j] = *((const uint2*)(xv + (long long)s * DIM) + lane);
        }
#pragma unroll
        for (int j = 0; j < BATCH; ++j) {                    // commit phase: masked fma
            float m = (j < cnt) ? 1.0f : 0.0f;
            ax = fmaf(m, __uint_as_float(vv[j].x << 16), ax);
            ay = fmaf(m, __uint_as_float(vv[j].x & 0xFFFF0000u), ay);
            az = fmaf(m, __uint_as_float(vv[j].y << 16), az);
            aw = fmaf(m, __uint_as_float(vv[j].y & 0xFFFF0000u), aw);
        }
    }
    ax = fmaxf(ax, 0.f); ay = fmaxf(ay, 0.f); az = fmaxf(az, 0.f); aw = fmaxf(aw, 0.f);
    if (DBF) {
        ushort4 o;
        o.x = f32_to_bf16_rne(ax); o.y = f32_to_bf16_rne(ay);
        o.z = f32_to_bf16_rne(az); o.w = f32_to_bf16_rne(aw);
        *((ushort4*)outv + (long long)r * (DIM / 4) + lane) = o;   // re-read next hop
    } else {
        f32x4 o = { ax, ay, az, aw };
        __builtin_nontemporal_store(o, (f32x4*)outv + (long long)r * (DIM / 4) + lane);
    }
}

// ---------- fused: sort B buckets (independent of gather1) || gather hop 1 ----------

__global__ void sortB_gather1(const u32* __restrict__ binned, const int* __restrict__ cnt,
                              int* __restrict__ sorted, int* __restrict__ rp33, int TBc,
                              int NBA_, int NBB_,
                              const u16* __restrict__ xpbf, u16* __restrict__ x_a1, int nA) {
    if ((int)blockIdx.x < NBB_) {
        sort_bucket(NBA_ + (int)blockIdx.x, binned, cnt, sorted, rp33, TBc);
        return;
    }
    gather_body<true>(xpbf, rp33, sorted, x_a1, nA, (int)blockIdx.x - NBB_);
}

__global__ void gather2(const u16* __restrict__ x_a1, const int* __restrict__ rp33B,
                        const int* __restrict__ sorted, float* __restrict__ x_p2, int nB) {
    gather_body<false>(x_a1, rp33B, sorted, x_p2, nB, (int)blockIdx.x);
}

// ---------- host ----------

extern "C" void kernel_launch(void* const* d_in, const int* in_sizes, int n_in,
                              void* d_out, int out_size, void* d_ws, size_t ws_size,
                              hipStream_t stream) {
    const float* x_paper = (const float*)d_in[0];
    const int* e_pa_src = (const int*)d_in[2];
    const int* e_pa_dst = (const int*)d_in[3];
    const int* e_ap_src = (const int*)d_in[4];
    const int* e_ap_dst = (const int*)d_in[5];

    const int nA = in_sizes[1] / DIM;         // 100000 authors (hop-1 dst)
    const int nB = in_sizes[0] / DIM;         // 200000 papers  (hop-2 dst)
    const int E1 = in_sizes[2];               // 1000000 (paper->author)
    const int E2 = in_sizes[4];               // 1000000 (author->paper)
    const int Etot = E1 + E2;

    const int NBA = (nA + RPB - 1) / RPB;     // 3125
    const int NBB = (nB + RPB - 1) / RPB;     // 6250
    const int TBc = NBA + NBB;                // 9375

    // ---- workspace (~213 MB; ws is ~819 MB per harness poison fill) ----
    size_t off = 0;
    auto alloc = [&](size_t bytes) { size_t o = off; off += (bytes + 255) & ~(size_t)255; return o; };
    size_t o_xpbf   = alloc((size_t)nB * DIM * sizeof(u16));          // 102.4 MB
    size_t o_xa1    = alloc((size_t)nA * DIM * sizeof(u16));          // 51.2 MB
    size_t o_cnt    = alloc((size_t)NG * TBc * sizeof(int));          // 0.3 MB
    size_t o_binned = alloc((size_t)NG * TBc * CAP * sizeof(u32));    // 38.4 MB
    size_t o_sorted = alloc((size_t)TBc * BCAP * sizeof(int));        // 19.2 MB
    size_t o_rp33   = alloc(((size_t)TBc * 33 + 1) * sizeof(int));    // 1.24 MB
    (void)ws_size;

    char* ws = (char*)d_ws;
    u16* xpbf   = (u16*)(ws + o_xpbf);
    u16* x_a1   = (u16*)(ws + o_xa1);
    int* cnt    = (int*)(ws + o_cnt);
    u32* binned = (u32*)(ws + o_binned);
    int* sorted = (int*)(ws + o_sorted);
    int* rp33   = (int*)(ws + o_rp33);
    float* x_p2 = (float*)d_out;

    hipMemsetAsync(cnt, 0, (size_t)NG * TBc * sizeof(int), stream);

    long long n4 = (long long)nB * DIM / 4;
    place_conv<<<PC_B, 256, 0, stream>>>(
        e_pa_src, e_pa_dst, e_ap_src, e_ap_dst, cnt, binned,
        TBc, NBA, E1, Etot, x_paper, xpbf, n4);

    // sort A buckets only (gather1's dependency)
    local_sortA<<<NBA, 256, 0, stream>>>(binned, cnt, sorted, rp33, TBc);

    // sort B buckets (gather2's dependency) hidden under gather hop 1
    sortB_gather1<<<NBB + (nA + 3) / 4, 256, 0, stream>>>(
        binned, cnt, sorted, rp33, TBc, NBA, NBB, xpbf, x_a1, nA);

    // hop 2: author -> paper, f32 relu(sum), NT stores
    gather2<<<(nB + 3) / 4, 256, 0, stream>>>(
        x_a1, rp33 + (size_t)NBA * 33, sorted, x_p2, nB);
}

// Round 10
// 302.982 us; speedup vs baseline: 1.1481x; 1.1481x over previous
//
#include <hip/hip_runtime.h>

#define DIM 256
#define RPB 32            // dst rows per bucket
#define LOG_RPB 5
#define NG 8              // XCD groups: g=(e>>8)&7 == blockIdx&7 (grid%8==0)
#define BATCH 16
#define CAP 128           // slab capacity per (g,bucket) cell; Poisson(<=40) -> 14 sigma
#define BCAP 512          // edges per bucket; Poisson(<=320) -> 10.7 sigma
#define PC_B 3072         // place_conv blocks (two roles of 1536; each %8==0)

typedef float f32x4 __attribute__((ext_vector_type(4)));
typedef unsigned int u32;
typedef unsigned short u16;

__device__ __forceinline__ u16 f32_to_bf16_rne(float f) {
    u32 u = __float_as_uint(f);
    return (u16)((u + 0x7FFFu + ((u >> 16) & 1u)) >> 16);
}

// ---------- fused slab placement (XCD-local) + f32->bf16 convert: ROUND-8 STATIC SPLIT ----
// Half the blocks place (latency/atomic-bound), half convert (BW-bound); the two roles
// overlap on orthogonal resources. Role interleave keeps place-role rank `sub` with
// sub&7 == blockIdx&7 == XCD, so cell (g=(e>>8)&7) counters/slabs stay in one L2.

__global__ void place_conv(const int* __restrict__ sA, const int* __restrict__ dA,
                           const int* __restrict__ sB, const int* __restrict__ dB,
                           int* __restrict__ cnt, u32* __restrict__ binned,
                           int TBc, int NBA_, int E1, int Etot,
                           const float* __restrict__ xin, u16* __restrict__ xbf,
                           long long n4) {
    int sub = ((int)blockIdx.x >> 4) * 8 + ((int)blockIdx.x & 7);  // role-local rank
    int half = (int)gridDim.x >> 1;                                // 1536, %8==0
    if ((((int)blockIdx.x >> 3) & 1) == 0) {
        // ---- place role ----
        int stride = half * (int)blockDim.x;                       // stride>>8 %8==0: g invariant
        for (int e = sub * (int)blockDim.x + (int)threadIdx.x; e < Etot; e += stride) {
            int g = (e >> 8) & (NG - 1);                           // == sub&7 == this XCD
            int s, d, b;
            if (e < E1) {
                s = __builtin_nontemporal_load(sA + e);
                d = __builtin_nontemporal_load(dA + e);
                b = d >> LOG_RPB;
            } else {
                int e2 = e - E1;
                s = __builtin_nontemporal_load(sB + e2);
                d = __builtin_nontemporal_load(dB + e2);
                b = NBA_ + (d >> LOG_RPB);
            }
            int cell = g * TBc + b;
            int old = atomicAdd(&cnt[cell], 1);                    // XCD-private counter
            if (old < CAP)
                binned[(long long)cell * CAP + old] = ((u32)s << LOG_RPB) | (u32)(d & (RPB - 1));
        }
    } else {
        // ---- convert role: x_paper f32 -> bf16 ----
        long long stride = (long long)half * blockDim.x;
        for (long long i = (long long)sub * blockDim.x + threadIdx.x; i < n4; i += stride) {
            f32x4 v = __builtin_nontemporal_load((const f32x4*)xin + i);
            ushort4 o;
            o.x = f32_to_bf16_rne(v.x); o.y = f32_to_bf16_rne(v.y);
            o.z = f32_to_bf16_rne(v.z); o.w = f32_to_bf16_rne(v.w);
            *((ushort4*)xbf + i) = o;                              // re-read by gather1: cached
        }
    }
}

// ---------- gather hop: one block per bucket. Sort own bucket into LDS, then gather
// own 32 rows. Self-contained: rows of bucket b only read bucket-b edges. ----------

template <bool DBF>
__global__ void __launch_bounds__(256)
gather_hop(const u32* __restrict__ binned, const int* __restrict__ cnt,
           const u16* __restrict__ xv, void* __restrict__ outv,
           int TBc, int bucket_base, int n) {
    __shared__ int sed[BCAP];          // src ids, grouped by local row
    __shared__ int rp[RPB + 1];        // local row offsets into sed
    __shared__ int c[RPB];
    __shared__ int cur[RPB];

    int tid = (int)threadIdx.x;
    int b = bucket_base + (int)blockIdx.x;

    // --- phase 1: histogram of local-row ids over the 8 XCD slabs ---
    if (tid < RPB) c[tid] = 0;
    __syncthreads();
#pragma unroll
    for (int g = 0; g < NG; ++g) {
        int cell = g * TBc + b;
        int m = cnt[cell]; m = (m < CAP) ? m : CAP;
        long long base = (long long)cell * CAP;
        for (int i = tid; i < m; i += 256)
            atomicAdd(&c[binned[base + i] & (RPB - 1)], 1);
    }
    __syncthreads();
    // --- phase 2: tiny serial prefix (32 entries) ---
    if (tid == 0) {
        int run = 0;
        for (int r = 0; r < RPB; ++r) { cur[r] = run; rp[r] = run; run += c[r]; }
        rp[RPB] = run;
    }
    __syncthreads();
    // --- phase 3: place src ids grouped by local row (native LDS int atomics) ---
#pragma unroll
    for (int g = 0; g < NG; ++g) {
        int cell = g * TBc + b;
        int m = cnt[cell]; m = (m < CAP) ? m : CAP;
        long long base = (long long)cell * CAP;
        for (int i = tid; i < m; i += 256) {
            u32 e = binned[base + i];
            int pos = atomicAdd(&cur[e & (RPB - 1)], 1);
            sed[pos] = (int)(e >> LOG_RPB);
        }
    }
    __syncthreads();

    // --- phase 4: gather 32 rows; wave w owns rows w, w+4, ... ---
    int lane = tid & 63, w = tid >> 6;
    int row0 = (int)blockIdx.x * RPB;
    for (int rr = w; rr < RPB; rr += 4) {
        int row = row0 + rr;
        if (row >= n) break;
        int beg = rp[rr];
        int end = rp[rr + 1];
        float ax = 0.f, ay = 0.f, az = 0.f, aw = 0.f;
        for (int i = beg; i < end; i += BATCH) {
            int m = end - i;
            m = (m < BATCH) ? m : BATCH;
            uint2 vv[BATCH];
#pragma unroll
            for (int j = 0; j < BATCH; ++j) {              // issue: 16 loads in flight
                int jj = (j < m) ? j : (m - 1);
                int s = sed[i + jj];                       // LDS broadcast (wave-uniform)
                vv[j] = *((const uint2*)(xv + (long long)s * DIM) + lane);
            }
#pragma unroll
            for (int j = 0; j < BATCH; ++j) {              // commit: masked fma
                float mk = (j < m) ? 1.0f : 0.0f;
                ax = fmaf(mk, __uint_as_float(vv[j].x << 16), ax);
                ay = fmaf(mk, __uint_as_float(vv[j].x & 0xFFFF0000u), ay);
                az = fmaf(mk, __uint_as_float(vv[j].y << 16), az);
                aw = fmaf(mk, __uint_as_float(vv[j].y & 0xFFFF0000u), aw);
            }
        }
        ax = fmaxf(ax, 0.f); ay = fmaxf(ay, 0.f); az = fmaxf(az, 0.f); aw = fmaxf(aw, 0.f);
        if (DBF) {
            ushort4 o;
            o.x = f32_to_bf16_rne(ax); o.y = f32_to_bf16_rne(ay);
            o.z = f32_to_bf16_rne(az); o.w = f32_to_bf16_rne(aw);
            *((ushort4*)outv + (long long)row * (DIM / 4) + lane) = o;  // re-read next hop
        } else {
            f32x4 o = { ax, ay, az, aw };
            __builtin_nontemporal_store(o, (f32x4*)outv + (long long)row * (DIM / 4) + lane);
        }
    }
}

// ---------- host ----------

extern "C" void kernel_launch(void* const* d_in, const int* in_sizes, int n_in,
                              void* d_out, int out_size, void* d_ws, size_t ws_size,
                              hipStream_t stream) {
    const float* x_paper = (const float*)d_in[0];
    const int* e_pa_src = (const int*)d_in[2];
    const int* e_pa_dst = (const int*)d_in[3];
    const int* e_ap_src = (const int*)d_in[4];
    const int* e_ap_dst = (const int*)d_in[5];

    const int nA = in_sizes[1] / DIM;         // 100000 authors (hop-1 dst)
    const int nB = in_sizes[0] / DIM;         // 200000 papers  (hop-2 dst)
    const int E1 = in_sizes[2];               // 1000000 (paper->author)
    const int E2 = in_sizes[4];               // 1000000 (author->paper)
    const int Etot = E1 + E2;

    const int NBA = (nA + RPB - 1) / RPB;     // 3125
    const int NBB = (nB + RPB - 1) / RPB;     // 6250
    const int TBc = NBA + NBB;                // 9375

    // ---- workspace (~192 MB) ----
    size_t off = 0;
    auto alloc = [&](size_t bytes) { size_t o = off; off += (bytes + 255) & ~(size_t)255; return o; };
    size_t o_xpbf   = alloc((size_t)nB * DIM * sizeof(u16));          // 102.4 MB
    size_t o_xa1    = alloc((size_t)nA * DIM * sizeof(u16));          // 51.2 MB
    size_t o_cnt    = alloc((size_t)NG * TBc * sizeof(int));          // 0.3 MB
    size_t o_binned = alloc((size_t)NG * TBc * CAP * sizeof(u32));    // 38.4 MB
    (void)ws_size;

    char* ws = (char*)d_ws;
    u16* xpbf   = (u16*)(ws + o_xpbf);
    u16* x_a1   = (u16*)(ws + o_xa1);
    int* cnt    = (int*)(ws + o_cnt);
    u32* binned = (u32*)(ws + o_binned);
    float* x_p2 = (float*)d_out;

    hipMemsetAsync(cnt, 0, (size_t)NG * TBc * sizeof(int), stream);

    long long n4 = (long long)nB * DIM / 4;
    place_conv<<<PC_B, 256, 0, stream>>>(
        e_pa_src, e_pa_dst, e_ap_src, e_ap_dst, cnt, binned,
        TBc, NBA, E1, Etot, x_paper, xpbf, n4);

    // hop 1: paper -> author, out = bf16(relu(sum)); each block sorts+gathers its bucket
    gather_hop<true><<<NBA, 256, 0, stream>>>(binned, cnt, xpbf, x_a1, TBc, 0, nA);

    // hop 2: author -> paper, out = f32 relu(sum), NT stores
    gather_hop<false><<<NBB, 256, 0, stream>>>(binned, cnt, x_a1, x_p2, TBc, NBA, nB);
}